// Round 1
// 1417.293 us; speedup vs baseline: 1.1813x; 1.1813x over previous
//
#include <hip/hip_runtime.h>
#include <hip/hip_bf16.h>

// Problem constants
#define NBANDS 5
#define BATCH  512
#define KQN    64     // queries per sample
#define DM     200    // model dim
#define NHEAD  4
#define HD     50     // head dim
#define HIDW   512    // router hidden
#define TKV    320    // NBANDS*KQN keys
#define FIN    64000  // NBANDS*KQN*DM
#define KSPLIT 20
#define KCH    3200   // FIN/KSPLIT
#define RCH    50     // KCH/64 chunks per block
#define KPAD   232    // padded K for bf16 LDS tiles (200 data + zeros)

typedef __bf16  bf16x8 __attribute__((ext_vector_type(8)));
typedef float   f32x4  __attribute__((ext_vector_type(4)));

static __device__ inline unsigned short f2bf(float f) {
    __hip_bfloat16 h = __float2bfloat16(f);
    return *reinterpret_cast<unsigned short*>(&h);
}
static __device__ inline float bf2f(unsigned short u) {
    union { unsigned int i; float f; } x;
    x.i = ((unsigned int)u) << 16;
    return x.f;
}

// ---------------------------------------------------------------------------
// K1: router GEMM via 3-product split-bf16 MFMA, with IN-KERNEL Markidis
// split of BOTH operands (w1 read as raw fp32 — hi+lo bf16 planes are the
// same 4 B/elem, so pre-conversion bought nothing and cost a 262 MB pass +
// 430 MB of dirty-plane writeback during this kernel).
// part[z][b][j] = sum_{ki in chunk z} flat[b,ki] * w1[j,ki]
//   flat[b,ki] = bands[band*6540800 + b*12800 + ki], band = ki/12800
//   (64-aligned chunks never cross a band: 12800 % 64 == 0; KCH=3200 divides
//    12800 so a z-slice sits entirely inside one band)
// acc += Ah*Bh + Ah*Bl + Al*Bh   (fp32 accumulate; residual ~2^-18 per term
//   -> logit error ~1e-5 << min top-2 gap ~3e-3 -> argmax-safe)
// Tile 64x64, BK=64, 4 waves each 16 rows x 64 cols. LDS 36.9 KB -> 4 blk/CU.
// Grid 8x8x20 = 1280 blocks (was 512 -> grid-limited 22% occupancy).
// XCD-chunked swizzle: each z-slice's 64 tiles co-reside on ONE XCD so the
// 8x A/B tile re-reads hit that XCD's 4 MB L2 (per-chunk slice set ~262 KB).
// ---------------------------------------------------------------------------
__global__ __launch_bounds__(256) void k_router_mfma(
    const float* __restrict__ bands, const float* __restrict__ w1,
    float* __restrict__ part)
{
    __shared__ __align__(16) unsigned short Ah[64][72];
    __shared__ __align__(16) unsigned short Al[64][72];
    __shared__ __align__(16) unsigned short Bh[64][72];
    __shared__ __align__(16) unsigned short Bl[64][72];

    // bijective XCD-cluster swizzle: 1280 blocks = 8 XCD x 160 logical
    const int lin     = (blockIdx.z << 6) + (blockIdx.y << 3) + blockIdx.x;
    const int logical = (lin & 7) * 160 + (lin >> 3);
    const int z   = logical >> 6;          // 0..19
    const int rem = logical & 63;
    const int j0  = (rem & 7) << 6;        // hid tile
    const int b0  = (rem >> 3) << 6;       // batch tile

    const int t  = threadIdx.x;
    const int w  = t >> 6, lane = t & 63;
    const int lm = lane & 15, quad = lane >> 4;
    const int m0 = w * 16;

    // staging index: 16 threads x float4 cover one 64-elem row; 4 rows/pass
    const int row0 = t >> 4, c4 = (t & 15) * 4;

    f32x4 acc[4];
#pragma unroll
    for (int nt = 0; nt < 4; ++nt) acc[nt] = (f32x4){0.f, 0.f, 0.f, 0.f};

    const int kbase = z * KCH;
    for (int chunk = 0; chunk < RCH; ++chunk) {
        const int kc = kbase + chunk * 64;
        const int band = kc / 12800;
        const float* abase = bands + (size_t)band * 6540800 + kc + c4;
        const float* bbase = w1 + (size_t)j0 * FIN + kc + c4;
        // ---- load to regs (overlaps previous chunk's MFMA) ----
        float4 av[4], bv[4];
#pragma unroll
        for (int r = 0; r < 4; ++r)
            av[r] = *(const float4*)(abase + (size_t)(b0 + row0 + r * 16) * 12800);
#pragma unroll
        for (int r = 0; r < 4; ++r)
            bv[r] = *(const float4*)(bbase + (size_t)(row0 + r * 16) * FIN);
        __syncthreads();   // previous chunk's MFMA LDS reads complete
        // ---- convert A and B to hi/lo, write LDS ----
#pragma unroll
        for (int r = 0; r < 4; ++r) {
            const int row = row0 + r * 16;
            ushort4 hh, ll;
            hh.x = f2bf(av[r].x); ll.x = f2bf(av[r].x - bf2f(hh.x));
            hh.y = f2bf(av[r].y); ll.y = f2bf(av[r].y - bf2f(hh.y));
            hh.z = f2bf(av[r].z); ll.z = f2bf(av[r].z - bf2f(hh.z));
            hh.w = f2bf(av[r].w); ll.w = f2bf(av[r].w - bf2f(hh.w));
            *(ushort4*)&Ah[row][c4] = hh;
            *(ushort4*)&Al[row][c4] = ll;
        }
#pragma unroll
        for (int r = 0; r < 4; ++r) {
            const int row = row0 + r * 16;
            ushort4 hh, ll;
            hh.x = f2bf(bv[r].x); ll.x = f2bf(bv[r].x - bf2f(hh.x));
            hh.y = f2bf(bv[r].y); ll.y = f2bf(bv[r].y - bf2f(hh.y));
            hh.z = f2bf(bv[r].z); ll.z = f2bf(bv[r].z - bf2f(hh.z));
            hh.w = f2bf(bv[r].w); ll.w = f2bf(bv[r].w - bf2f(hh.w));
            *(ushort4*)&Bh[row][c4] = hh;
            *(ushort4*)&Bl[row][c4] = ll;
        }
        __syncthreads();
        // ---- 3-product MFMA ----
#pragma unroll
        for (int ks = 0; ks < 2; ++ks) {
            const int ka = ks * 32 + quad * 8;
            const bf16x8 a_h = *(const bf16x8*)&Ah[m0 + lm][ka];
            const bf16x8 a_l = *(const bf16x8*)&Al[m0 + lm][ka];
#pragma unroll
            for (int nt = 0; nt < 4; ++nt) {
                const bf16x8 b_h = *(const bf16x8*)&Bh[nt * 16 + lm][ka];
                const bf16x8 b_l = *(const bf16x8*)&Bl[nt * 16 + lm][ka];
                acc[nt] = __builtin_amdgcn_mfma_f32_16x16x32_bf16(a_h, b_h, acc[nt], 0, 0, 0);
                acc[nt] = __builtin_amdgcn_mfma_f32_16x16x32_bf16(a_l, b_h, acc[nt], 0, 0, 0);
                acc[nt] = __builtin_amdgcn_mfma_f32_16x16x32_bf16(a_h, b_l, acc[nt], 0, 0, 0);
            }
        }
    }
    // epilogue: row (batch) = b0+m0+quad*4+reg, col (j) = j0+nt*16+lm
    float* po = part + (size_t)z * (BATCH * HIDW);
#pragma unroll
    for (int nt = 0; nt < 4; ++nt) {
        const int jj = j0 + nt * 16 + lm;
#pragma unroll
        for (int reg = 0; reg < 4; ++reg) {
            const int bb = b0 + m0 + quad * 4 + reg;
            po[(size_t)bb * HIDW + jj] = acc[nt][reg];
        }
    }
}

// ---------------------------------------------------------------------------
// K2: h = relu(sum_z part + b1)
// ---------------------------------------------------------------------------
__global__ __launch_bounds__(256) void k_reduce_relu(
    const float* __restrict__ part, const float* __restrict__ b1,
    float* __restrict__ h)
{
    const int tid = blockIdx.x * 256 + threadIdx.x;  // < BATCH*HIDW
    float s = b1[tid & (HIDW - 1)];
#pragma unroll
    for (int z = 0; z < KSPLIT; ++z) s += part[z * (BATCH * HIDW) + tid];
    h[tid] = fmaxf(s, 0.f);
}

// ---------------------------------------------------------------------------
// K2b: pre-convert in_proj rows 200..599 (wk|wv) to bf16, K padded to 232.
// ---------------------------------------------------------------------------
__global__ __launch_bounds__(256) void k_wprep(
    const float* __restrict__ ipw, unsigned short* __restrict__ Wb)
{
    const int j = blockIdx.x;        // 0..399
    const int c = threadIdx.x;       // 0..255 (232 active)
    if (c < KPAD) {
        const float v = (c < DM) ? ipw[(size_t)(DM + j) * DM + c] : 0.f;
        Wb[(size_t)j * KPAD + c] = f2bf(v);
    }
}

// ---------------------------------------------------------------------------
// K3: logits = h @ w2^T + b2 ; sel = argmax (softmax is monotonic -> skip it)
// ---------------------------------------------------------------------------
__global__ __launch_bounds__(256) void k_argmax(
    const float* __restrict__ h, const float* __restrict__ w2,
    const float* __restrict__ b2, int* __restrict__ sel)
{
    __shared__ float red[NBANDS][256];
    const int b = blockIdx.x, t = threadIdx.x;
    float acc[NBANDS] = {0.f, 0.f, 0.f, 0.f, 0.f};
    for (int j = t; j < HIDW; j += 256) {
        const float hv = h[b * HIDW + j];
#pragma unroll
        for (int n = 0; n < NBANDS; ++n)
            acc[n] = fmaf(hv, w2[n * HIDW + j], acc[n]);
    }
#pragma unroll
    for (int n = 0; n < NBANDS; ++n) red[n][t] = acc[n];
    __syncthreads();
    for (int s = 128; s > 0; s >>= 1) {
        if (t < s) {
#pragma unroll
            for (int n = 0; n < NBANDS; ++n) red[n][t] += red[n][t + s];
        }
        __syncthreads();
    }
    if (t == 0) {
        int best = 0;
        float bv = red[0][0] + b2[0];
        for (int n = 1; n < NBANDS; ++n) {
            const float v = red[n][0] + b2[n];
            if (v > bv) { bv = v; best = n; }
        }
        sel[b] = best;
    }
}

// ---------------------------------------------------------------------------
// K4: q projection for the selected band (fp32 — feeds scores, keep precise)
// ---------------------------------------------------------------------------
__global__ __launch_bounds__(256) void k_qproj(
    const float* __restrict__ bands, const int* __restrict__ sel,
    const float* __restrict__ ipw, const float* __restrict__ ipb,
    float* __restrict__ q)
{
    __shared__ float xs[64][204];
    const int b = blockIdx.x;
    const int t = threadIdx.x;
    const int band = sel[b];
    for (int idx = t; idx < KQN * DM; idx += 256) {
        const int r = idx / DM, col = idx - r * DM;
        xs[r][col] = bands[(size_t)((band * BATCH + b) * KQN + r) * DM + col];
    }
    __syncthreads();
    const int r = t & 31, c = t >> 5;
    for (int oo = c; oo < DM; oo += 8) {
        const float* wrow = ipw + (size_t)oo * DM;   // wq rows 0..199
        const float bias = ipb[oo];
        float4 s0 = {0, 0, 0, 0}, s1 = {0, 0, 0, 0};
        for (int in = 0; in < DM; in += 4) {
            const float4 w4 = *(const float4*)(wrow + in);
            const float4 x0 = *(const float4*)&xs[r][in];
            const float4 x1 = *(const float4*)&xs[r + 32][in];
            s0.x = fmaf(x0.x, w4.x, s0.x); s0.y = fmaf(x0.y, w4.y, s0.y);
            s0.z = fmaf(x0.z, w4.z, s0.z); s0.w = fmaf(x0.w, w4.w, s0.w);
            s1.x = fmaf(x1.x, w4.x, s1.x); s1.y = fmaf(x1.y, w4.y, s1.y);
            s1.z = fmaf(x1.z, w4.z, s1.z); s1.w = fmaf(x1.w, w4.w, s1.w);
        }
        const float a0 = bias + ((s0.x + s0.y) + (s0.z + s0.w));
        const float a1 = bias + ((s1.x + s1.y) + (s1.z + s1.w));
        q[(size_t)(b * KQN + r) * DM + oo] = a0;
        q[(size_t)(b * KQN + r + 32) * DM + oo] = a1;
    }
}

// ---------------------------------------------------------------------------
// K5: kv projection as bf16 MFMA GEMM (unchanged).
// ---------------------------------------------------------------------------
__global__ __launch_bounds__(256) void k_kvproj(
    const float* __restrict__ bands, const unsigned short* __restrict__ Wb,
    const float* __restrict__ ipb, __hip_bfloat16* __restrict__ Kp,
    __hip_bfloat16* __restrict__ Vp)
{
    __shared__ __align__(16) unsigned short Xs[64][KPAD];
    __shared__ __align__(16) unsigned short Ws[80][KPAD];
    __shared__ float Bbias[80];
    const int t  = threadIdx.x;
    const int M0 = blockIdx.x * 64;     // global kv row base
    const int n0 = blockIdx.y * 80;     // output col base (0..400)

    {
        const float4* wsrc = (const float4*)(Wb + (size_t)n0 * KPAD);
        float4* wdst = (float4*)&Ws[0][0];
        for (int i = t; i < 2320; i += 256) wdst[i] = wsrc[i];
    }
    if (t < 80) Bbias[t] = ipb[DM + n0 + t];
    for (int i = t; i < 64 * 50; i += 256) {
        const int r = i / 50, g = i - r * 50;
        const int gg = M0 + r;
        const int bb = gg / TKV, tk = gg - bb * TKV;
        const int band = tk >> 6, kk = tk & 63;
        const float4 x4 = *(const float4*)(bands
            + ((size_t)((band * BATCH + bb) * KQN + kk)) * DM + g * 4);
        ushort4 u;
        u.x = f2bf(x4.x); u.y = f2bf(x4.y); u.z = f2bf(x4.z); u.w = f2bf(x4.w);
        *(ushort4*)&Xs[r][g * 4] = u;
    }
    for (int i = t; i < 64 * 8; i += 256) {
        const int r = i >> 3, g = i & 7;
        ushort4 z; z.x = 0; z.y = 0; z.z = 0; z.w = 0;
        *(ushort4*)&Xs[r][DM + g * 4] = z;
    }
    __syncthreads();

    const int w = t >> 6, lane = t & 63;
    const int lm = lane & 15, quad = lane >> 4;
    const int m0 = w * 16;
    f32x4 acc[5];
#pragma unroll
    for (int nt = 0; nt < 5; ++nt) acc[nt] = (f32x4){0.f, 0.f, 0.f, 0.f};

#pragma unroll
    for (int ks = 0; ks < 7; ++ks) {                 // 7*32 = 224 >= 200
        const int ka = ks * 32 + quad * 8;
        const bf16x8 a = *(const bf16x8*)&Xs[m0 + lm][ka];
#pragma unroll
        for (int nt = 0; nt < 5; ++nt) {
            const bf16x8 bb8 = *(const bf16x8*)&Ws[nt * 16 + lm][ka];
            acc[nt] = __builtin_amdgcn_mfma_f32_16x16x32_bf16(a, bb8, acc[nt], 0, 0, 0);
        }
    }
#pragma unroll
    for (int nt = 0; nt < 5; ++nt) {
        const int col = n0 + nt * 16 + lm;
        const float bias = Bbias[nt * 16 + lm];
#pragma unroll
        for (int reg = 0; reg < 4; ++reg) {
            const int grow = M0 + m0 + quad * 4 + reg;
            const float v = acc[nt][reg] + bias;
            if (col < DM) Kp[(size_t)grow * DM + col] = __float2bfloat16(v);
            else          Vp[(size_t)grow * DM + (col - DM)] = __float2bfloat16(v);
        }
    }
}

// ---------------------------------------------------------------------------
// K6: MFMA attention per (b, head) (unchanged).
// ---------------------------------------------------------------------------
__global__ __launch_bounds__(256) void k_attn(
    const float* __restrict__ qbuf, const __hip_bfloat16* __restrict__ Kp,
    const __hip_bfloat16* __restrict__ Vp, float* __restrict__ obuf)
{
    __shared__ __align__(16) unsigned short Qs[64][72];    // [query][k 0..63]
    __shared__ __align__(16) unsigned short KP[320][72];   // [key][k 0..63]
    __shared__ __align__(16) unsigned short Vt[64][328];   // [e][key]
    __shared__ __align__(16) unsigned short Ps[64][328];   // [query][key]
    const int b = blockIdx.x, hh = blockIdx.y;
    const int t = threadIdx.x;

    for (int idx = t; idx < 64 * 64; idx += 256) {
        const int r = idx >> 6, e = idx & 63;
        const float v = (e < HD) ? qbuf[(size_t)(b * KQN + r) * DM + hh * HD + e] : 0.f;
        Qs[r][e] = f2bf(v);
    }
    const unsigned short* kbase = (const unsigned short*)Kp + (size_t)b * TKV * DM + hh * HD;
    for (int idx = t; idx < 320 * 25; idx += 256) {
        const int key = idx / 25, g = idx - key * 25;
        *(unsigned int*)&KP[key][g * 2] =
            *(const unsigned int*)(kbase + (size_t)key * DM + g * 2);
    }
    for (int idx = t; idx < 320 * 7; idx += 256) {   // zero k-pad [50,64)
        const int key = idx / 7, g = idx - key * 7;
        *(unsigned int*)&KP[key][50 + g * 2] = 0;
    }
    const unsigned short* vbase = (const unsigned short*)Vp + (size_t)b * TKV * DM + hh * HD;
    for (int idx = t; idx < 320 * 25; idx += 256) {
        const int key = idx / 25, g = idx - key * 25;
        const unsigned int v = *(const unsigned int*)(vbase + (size_t)key * DM + g * 2);
        Vt[g * 2][key]     = (unsigned short)(v & 0xffffu);
        Vt[g * 2 + 1][key] = (unsigned short)(v >> 16);
    }
    __syncthreads();

    const int w = t >> 6, lane = t & 63;
    const int lm = lane & 15, quad = lane >> 4;
    const int m0 = w * 16;

    f32x4 s[20];
#pragma unroll
    for (int nt = 0; nt < 20; ++nt) s[nt] = (f32x4){0.f, 0.f, 0.f, 0.f};
#pragma unroll
    for (int ks = 0; ks < 2; ++ks) {
        const int ka = ks * 32 + quad * 8;
        const bf16x8 a = *(const bf16x8*)&Qs[m0 + lm][ka];
#pragma unroll
        for (int nt = 0; nt < 20; ++nt) {
            const bf16x8 bb8 = *(const bf16x8*)&KP[nt * 16 + lm][ka];
            s[nt] = __builtin_amdgcn_mfma_f32_16x16x32_bf16(a, bb8, s[nt], 0, 0, 0);
        }
    }

    const float scale = 0.14142135623730951f;  // 1/sqrt(50)
    float inv[4];
#pragma unroll
    for (int reg = 0; reg < 4; ++reg) {
        float mx = -1e30f;
#pragma unroll
        for (int nt = 0; nt < 20; ++nt) {
            const float sv = s[nt][reg] * scale;
            s[nt][reg] = sv;
            mx = fmaxf(mx, sv);
        }
#pragma unroll
        for (int off = 1; off < 16; off <<= 1)
            mx = fmaxf(mx, __shfl_xor(mx, off, 64));
        float lsum = 0.f;
#pragma unroll
        for (int nt = 0; nt < 20; ++nt) {
            const float p = __expf(s[nt][reg] - mx);
            s[nt][reg] = p;
            lsum += p;
        }
#pragma unroll
        for (int off = 1; off < 16; off <<= 1)
            lsum += __shfl_xor(lsum, off, 64);
        inv[reg] = 1.f / lsum;
    }
#pragma unroll
    for (int reg = 0; reg < 4; ++reg) {
        const int row = m0 + quad * 4 + reg;
#pragma unroll
        for (int nt = 0; nt < 20; ++nt)
            Ps[row][nt * 16 + lm] = f2bf(s[nt][reg]);
    }
    __syncthreads();

    f32x4 o[4];
#pragma unroll
    for (int nt = 0; nt < 4; ++nt) o[nt] = (f32x4){0.f, 0.f, 0.f, 0.f};
#pragma unroll
    for (int ks = 0; ks < 10; ++ks) {
        const int ka = ks * 32 + quad * 8;
        const bf16x8 a = *(const bf16x8*)&Ps[m0 + lm][ka];
#pragma unroll
        for (int nt = 0; nt < 4; ++nt) {
            const bf16x8 bb8 = *(const bf16x8*)&Vt[nt * 16 + lm][ka];
            o[nt] = __builtin_amdgcn_mfma_f32_16x16x32_bf16(a, bb8, o[nt], 0, 0, 0);
        }
    }
    float* op = obuf + (size_t)(b * KQN) * DM + hh * HD;
#pragma unroll
    for (int nt = 0; nt < 4; ++nt) {
        const int e = nt * 16 + lm;
        if (e < HD) {
#pragma unroll
            for (int reg = 0; reg < 4; ++reg) {
                const int row = m0 + quad * 4 + reg;
                op[(size_t)row * DM + e] = o[nt][reg] * inv[reg];
            }
        }
    }
}

// ---------------------------------------------------------------------------
// K7: out = o @ out_w^T + out_b
// ---------------------------------------------------------------------------
__global__ __launch_bounds__(256) void k_outproj(
    const float* __restrict__ obuf, const float* __restrict__ outw,
    const float* __restrict__ outb, float* __restrict__ out)
{
    __shared__ float xs[64][204];
    const int b = blockIdx.x;
    const int t = threadIdx.x;
    for (int idx = t; idx < KQN * DM; idx += 256) {
        const int r = idx / DM, col = idx - r * DM;
        xs[r][col] = obuf[(size_t)(b * KQN + r) * DM + col];
    }
    __syncthreads();
    const int r = t & 31, c = t >> 5;
    for (int oo = c; oo < DM; oo += 8) {
        const float* wrow = outw + (size_t)oo * DM;
        const float bias = outb[oo];
        float4 s0 = {0, 0, 0, 0}, s1 = {0, 0, 0, 0};
        for (int in = 0; in < DM; in += 4) {
            const float4 w4 = *(const float4*)(wrow + in);
            const float4 x0 = *(const float4*)&xs[r][in];
            const float4 x1 = *(const float4*)&xs[r + 32][in];
            s0.x = fmaf(x0.x, w4.x, s0.x); s0.y = fmaf(x0.y, w4.y, s0.y);
            s0.z = fmaf(x0.z, w4.z, s0.z); s0.w = fmaf(x0.w, w4.w, s0.w);
            s1.x = fmaf(x1.x, w4.x, s1.x); s1.y = fmaf(x1.y, w4.y, s1.y);
            s1.z = fmaf(x1.z, w4.z, s1.z); s1.w = fmaf(x1.w, w4.w, s1.w);
        }
        const float a0 = bias + ((s0.x + s0.y) + (s0.z + s0.w));
        const float a1 = bias + ((s1.x + s1.y) + (s1.z + s1.w));
        out[(size_t)(b * KQN + r) * DM + oo] = a0;
        out[(size_t)(b * KQN + r + 32) * DM + oo] = a1;
    }
}

// ---------------------------------------------------------------------------
// Workspace layout (phase-overlapped, peak 183.7 MB < 193 MB):
//   sel  int [512]             @ 0           (2,048)        [live whole run]
//   -- phase 1 (router; no wH/wL anymore — w1 read fp32 directly):
//   part fp32 [20][512][512]   @ 4096        (20,971,520)
//   h    fp32 [512][512]       @ 20,975,616  ( 1,048,576)
//   (both live inside the later q region; dead before k_qproj writes q)
//   -- phase 2 (attn; launched after argmax):
//   q    fp32 [512][64][200]   @ 4096        (26,214,400)
//   Wb   bf16 [400][232]       @ 26,218,496  (   185,600)
//   Kp   bf16 [512][320][200]  @ 26,404,096  (65,536,000)
//   Vp   bf16 [512][320][200]  @ 91,940,096  (65,536,000)
//   obuf fp32 [512][64][200]   @ 157,476,096 (26,214,400)  -> ends 183,690,496
// ---------------------------------------------------------------------------
extern "C" void kernel_launch(void* const* d_in, const int* in_sizes, int n_in,
                              void* d_out, int out_size, void* d_ws, size_t ws_size,
                              hipStream_t stream)
{
    const float* bands = (const float*)d_in[0];
    const float* w1    = (const float*)d_in[1];
    const float* b1    = (const float*)d_in[2];
    const float* w2    = (const float*)d_in[3];
    const float* b2    = (const float*)d_in[4];
    const float* ipw   = (const float*)d_in[5];
    const float* ipb   = (const float*)d_in[6];
    const float* outw  = (const float*)d_in[7];
    const float* outb  = (const float*)d_in[8];
    float* out = (float*)d_out;

    if (ws_size < (size_t)192940032) return;

    char* ws = (char*)d_ws;
    int*   sel  = (int*)  (ws + 0);
    float* part = (float*)(ws + 4096);
    float* h    = (float*)(ws + 20975616);
    float* q    = (float*)(ws + 4096);                 // phase 2 (part/h dead)
    unsigned short* Wb = (unsigned short*)(ws + 26218496);
    __hip_bfloat16* Kp = (__hip_bfloat16*)(ws + 26404096);
    __hip_bfloat16* Vp = (__hip_bfloat16*)(ws + 91940096);
    float* obuf = (float*)(ws + 157476096);

    k_router_mfma<<<dim3(8, 8, KSPLIT), 256, 0, stream>>>(bands, w1, part);
    k_reduce_relu<<<(BATCH * HIDW) / 256, 256, 0, stream>>>(part, b1, h);
    k_argmax<<<BATCH, 256, 0, stream>>>(h, w2, b2, sel);
    // ---- phase 2: phase-1 buffers (part/h) are dead from here ----
    k_wprep<<<400, 256, 0, stream>>>(ipw, Wb);
    k_qproj<<<BATCH, 256, 0, stream>>>(bands, sel, ipw, ipb, q);
    k_kvproj<<<dim3(2560, 5), 256, 0, stream>>>(bands, Wb, ipb, Kp, Vp);
    k_attn<<<dim3(BATCH, NHEAD), 256, 0, stream>>>(q, Kp, Vp, obuf);
    k_outproj<<<BATCH, 256, 0, stream>>>(obuf, outw, outb, out);
}

// Round 2
// 935.663 us; speedup vs baseline: 1.7893x; 1.5147x over previous
//
#include <hip/hip_runtime.h>
#include <hip/hip_bf16.h>

// Problem constants
#define NBANDS 5
#define BATCH  512
#define KQN    64     // queries per sample
#define DM     200    // model dim
#define NHEAD  4
#define HD     50     // head dim
#define HIDW   512    // router hidden
#define TKV    320    // NBANDS*KQN keys
#define FIN    64000  // NBANDS*KQN*DM
#define KSPLIT 20
#define KCH    3200   // FIN/KSPLIT
#define RCH    50     // KCH/64 chunks per block
#define KPAD   232    // padded K for bf16 LDS tiles (200 data + zeros)
#define NTT    13     // N-tiles of 16 covering 200 (13*16=208)
#define KST    7      // K-steps of 32 covering 200 (7*32=224)
#define PLANE_ELEMS (KST * NTT * 64 * 8)   // 46592 ushorts = 93,184 B

typedef __bf16  bf16x8 __attribute__((ext_vector_type(8)));
typedef float   f32x4  __attribute__((ext_vector_type(4)));

static __device__ inline unsigned short f2bf(float f) {
    __hip_bfloat16 h = __float2bfloat16(f);
    return *reinterpret_cast<unsigned short*>(&h);
}
static __device__ inline float bf2f(unsigned short u) {
    union { unsigned int i; float f; } x;
    x.i = ((unsigned int)u) << 16;
    return x.f;
}
static __device__ inline bf16x8 bf8zero() {
    union { bf16x8 v; unsigned int u[4]; } z;
    z.u[0] = z.u[1] = z.u[2] = z.u[3] = 0u;
    return z.v;
}
// Markidis split of 8 consecutive fp32 into hi/lo bf16x8
static __device__ inline void split8(const float4& a, const float4& b,
                                     bf16x8& hi, bf16x8& lo) {
    union { bf16x8 v; unsigned short u[8]; } H, L;
    const float xs[8] = {a.x, a.y, a.z, a.w, b.x, b.y, b.z, b.w};
#pragma unroll
    for (int i = 0; i < 8; ++i) {
        H.u[i] = f2bf(xs[i]);
        L.u[i] = f2bf(xs[i] - bf2f(H.u[i]));
    }
    hi = H.v; lo = L.v;
}

// ---------------------------------------------------------------------------
// K1: router GEMM via 3-product split-bf16 MFMA, in-kernel Markidis split of
// both operands. Grid 8x8x20 = 1280 blocks, XCD-clustered so each z-slice's
// 64 (j,b) tiles co-reside on one XCD (slice working set ~262 KB << 4 MB L2).
// acc += Ah*Bh + Ah*Bl + Al*Bh  (fp32 accum; logit err ~1e-5 << top-2 gap)
// ---------------------------------------------------------------------------
__global__ __launch_bounds__(256) void k_router_mfma(
    const float* __restrict__ bands, const float* __restrict__ w1,
    float* __restrict__ part)
{
    __shared__ __align__(16) unsigned short Ah[64][72];
    __shared__ __align__(16) unsigned short Al[64][72];
    __shared__ __align__(16) unsigned short Bh[64][72];
    __shared__ __align__(16) unsigned short Bl[64][72];

    // bijective XCD-cluster swizzle: 1280 blocks = 8 XCD x 160 logical
    const int lin     = (blockIdx.z << 6) + (blockIdx.y << 3) + blockIdx.x;
    const int logical = (lin & 7) * 160 + (lin >> 3);
    const int z   = logical >> 6;          // 0..19
    const int rem = logical & 63;
    const int j0  = (rem & 7) << 6;        // hid tile
    const int b0  = (rem >> 3) << 6;       // batch tile

    const int t  = threadIdx.x;
    const int w  = t >> 6, lane = t & 63;
    const int lm = lane & 15, quad = lane >> 4;
    const int m0 = w * 16;

    const int row0 = t >> 4, c4 = (t & 15) * 4;

    f32x4 acc[4];
#pragma unroll
    for (int nt = 0; nt < 4; ++nt) acc[nt] = (f32x4){0.f, 0.f, 0.f, 0.f};

    const int kbase = z * KCH;
    for (int chunk = 0; chunk < RCH; ++chunk) {
        const int kc = kbase + chunk * 64;
        const int band = kc / 12800;
        const float* abase = bands + (size_t)band * 6540800 + kc + c4;
        const float* bbase = w1 + (size_t)j0 * FIN + kc + c4;
        float4 av[4], bv[4];
#pragma unroll
        for (int r = 0; r < 4; ++r)
            av[r] = *(const float4*)(abase + (size_t)(b0 + row0 + r * 16) * 12800);
#pragma unroll
        for (int r = 0; r < 4; ++r)
            bv[r] = *(const float4*)(bbase + (size_t)(row0 + r * 16) * FIN);
        __syncthreads();   // previous chunk's MFMA LDS reads complete
#pragma unroll
        for (int r = 0; r < 4; ++r) {
            const int row = row0 + r * 16;
            ushort4 hh, ll;
            hh.x = f2bf(av[r].x); ll.x = f2bf(av[r].x - bf2f(hh.x));
            hh.y = f2bf(av[r].y); ll.y = f2bf(av[r].y - bf2f(hh.y));
            hh.z = f2bf(av[r].z); ll.z = f2bf(av[r].z - bf2f(hh.z));
            hh.w = f2bf(av[r].w); ll.w = f2bf(av[r].w - bf2f(hh.w));
            *(ushort4*)&Ah[row][c4] = hh;
            *(ushort4*)&Al[row][c4] = ll;
        }
#pragma unroll
        for (int r = 0; r < 4; ++r) {
            const int row = row0 + r * 16;
            ushort4 hh, ll;
            hh.x = f2bf(bv[r].x); ll.x = f2bf(bv[r].x - bf2f(hh.x));
            hh.y = f2bf(bv[r].y); ll.y = f2bf(bv[r].y - bf2f(hh.y));
            hh.z = f2bf(bv[r].z); ll.z = f2bf(bv[r].z - bf2f(hh.z));
            hh.w = f2bf(bv[r].w); ll.w = f2bf(bv[r].w - bf2f(hh.w));
            *(ushort4*)&Bh[row][c4] = hh;
            *(ushort4*)&Bl[row][c4] = ll;
        }
        __syncthreads();
#pragma unroll
        for (int ks = 0; ks < 2; ++ks) {
            const int ka = ks * 32 + quad * 8;
            const bf16x8 a_h = *(const bf16x8*)&Ah[m0 + lm][ka];
            const bf16x8 a_l = *(const bf16x8*)&Al[m0 + lm][ka];
#pragma unroll
            for (int nt = 0; nt < 4; ++nt) {
                const bf16x8 b_h = *(const bf16x8*)&Bh[nt * 16 + lm][ka];
                const bf16x8 b_l = *(const bf16x8*)&Bl[nt * 16 + lm][ka];
                acc[nt] = __builtin_amdgcn_mfma_f32_16x16x32_bf16(a_h, b_h, acc[nt], 0, 0, 0);
                acc[nt] = __builtin_amdgcn_mfma_f32_16x16x32_bf16(a_l, b_h, acc[nt], 0, 0, 0);
                acc[nt] = __builtin_amdgcn_mfma_f32_16x16x32_bf16(a_h, b_l, acc[nt], 0, 0, 0);
            }
        }
    }
    float* po = part + (size_t)z * (BATCH * HIDW);
#pragma unroll
    for (int nt = 0; nt < 4; ++nt) {
        const int jj = j0 + nt * 16 + lm;
#pragma unroll
        for (int reg = 0; reg < 4; ++reg) {
            const int bb = b0 + m0 + quad * 4 + reg;
            po[(size_t)bb * HIDW + jj] = acc[nt][reg];
        }
    }
}

// ---------------------------------------------------------------------------
// K2: h = relu(sum_z part + b1)
// ---------------------------------------------------------------------------
__global__ __launch_bounds__(256) void k_reduce_relu(
    const float* __restrict__ part, const float* __restrict__ b1,
    float* __restrict__ h)
{
    const int tid = blockIdx.x * 256 + threadIdx.x;  // < BATCH*HIDW
    float s = b1[tid & (HIDW - 1)];
#pragma unroll
    for (int z = 0; z < KSPLIT; ++z) s += part[z * (BATCH * HIDW) + tid];
    h[tid] = fmaxf(s, 0.f);
}

// ---------------------------------------------------------------------------
// K2b: pre-convert in_proj rows 200..599 (wk|wv) to bf16, K padded to 232.
// ---------------------------------------------------------------------------
__global__ __launch_bounds__(256) void k_wprep(
    const float* __restrict__ ipw, unsigned short* __restrict__ Wb)
{
    const int j = blockIdx.x;        // 0..399
    const int c = threadIdx.x;       // 0..255 (232 active)
    if (c < KPAD) {
        const float v = (c < DM) ? ipw[(size_t)(DM + j) * DM + c] : 0.f;
        Wb[(size_t)j * KPAD + c] = f2bf(v);
    }
}

// ---------------------------------------------------------------------------
// K2c: pack wq (ipw rows 0..199) and out_w into FRAGMENT-MAJOR Markidis
// hi/lo bf16 planes: elem idx = ((ks*13+nt)*64 + lane)*8 + e  maps to
// W[nt*16 + (lane&15)][ks*32 + (lane>>4)*8 + e], zero-padded past 200.
// Consumer's per-(ks,nt) fragment load is then lane-contiguous (1 KB/wave,
// perfectly coalesced, no LDS needed).
// ---------------------------------------------------------------------------
__global__ __launch_bounds__(256) void k_wpack(
    const float* __restrict__ ipw, const float* __restrict__ outw,
    unsigned short* __restrict__ WqHp, unsigned short* __restrict__ WqLp,
    unsigned short* __restrict__ OwHp, unsigned short* __restrict__ OwLp)
{
    const int p = blockIdx.x;          // 0..90 : ks*13+nt
    const int ks = p / NTT, nt = p - ks * NTT;
    const int t = threadIdx.x;
    const int lane = t >> 2, e0 = (t & 3) * 2;
    const int lm = lane & 15, quad = lane >> 4;
    const int row = nt * 16 + lm;
    const int k  = ks * 32 + quad * 8 + e0;
    const float* src = (blockIdx.y == 0) ? ipw : outw;   // wq = ipw rows 0..199
    unsigned short* dh = (blockIdx.y == 0) ? WqHp : OwHp;
    unsigned short* dl = (blockIdx.y == 0) ? WqLp : OwLp;
    float v0 = 0.f, v1 = 0.f;
    if (row < DM && k < DM) {          // k even, so k<200 => k+1<=199 valid
        v0 = src[(size_t)row * DM + k];
        v1 = src[(size_t)row * DM + k + 1];
    }
    const int off = (p << 9) + (lane << 3) + e0;
    const unsigned short h0 = f2bf(v0), h1 = f2bf(v1);
    dh[off]     = h0;
    dh[off + 1] = h1;
    dl[off]     = f2bf(v0 - bf2f(h0));
    dl[off + 1] = f2bf(v1 - bf2f(h1));
}

// ---------------------------------------------------------------------------
// K3: logits = h @ w2^T + b2 ; sel = argmax (softmax is monotonic -> skip it)
// ---------------------------------------------------------------------------
__global__ __launch_bounds__(256) void k_argmax(
    const float* __restrict__ h, const float* __restrict__ w2,
    const float* __restrict__ b2, int* __restrict__ sel)
{
    __shared__ float red[NBANDS][256];
    const int b = blockIdx.x, t = threadIdx.x;
    float acc[NBANDS] = {0.f, 0.f, 0.f, 0.f, 0.f};
    for (int j = t; j < HIDW; j += 256) {
        const float hv = h[b * HIDW + j];
#pragma unroll
        for (int n = 0; n < NBANDS; ++n)
            acc[n] = fmaf(hv, w2[n * HIDW + j], acc[n]);
    }
#pragma unroll
    for (int n = 0; n < NBANDS; ++n) red[n][t] = acc[n];
    __syncthreads();
    for (int s = 128; s > 0; s >>= 1) {
        if (t < s) {
#pragma unroll
            for (int n = 0; n < NBANDS; ++n) red[n][t] += red[n][t + s];
        }
        __syncthreads();
    }
    if (t == 0) {
        int best = 0;
        float bv = red[0][0] + b2[0];
        for (int n = 1; n < NBANDS; ++n) {
            const float v = red[n][0] + b2[n];
            if (v > bv) { bv = v; best = n; }
        }
        sel[b] = best;
    }
}

// ---------------------------------------------------------------------------
// Shared MFMA core for the two [64x200]@[200x200]^T projections.
// 3-product Markidis split (err ~1e-5 rel, fp32-class). A-side fragments
// loaded per-lane from global fp32 and split in registers (reused across all
// 13 N-tiles); B-side from fragment-major packed planes (coalesced).
// 4 waves x 16 rows; acc = 13 x f32x4 = 52 VGPR.
// ---------------------------------------------------------------------------
template<bool BF16OUT>
static __device__ inline void proj_core(
    const float* __restrict__ x0,            // 64 rows x 200 fp32, stride DM
    const unsigned short* __restrict__ Ph,   // packed hi plane
    const unsigned short* __restrict__ Pl,   // packed lo plane
    const float* __restrict__ bias,          // 200
    void* __restrict__ outp)                 // 64 rows x 200 (bf16 or f32)
{
    const int t = threadIdx.x;
    const int w = t >> 6, lane = t & 63;
    const int lm = lane & 15, quad = lane >> 4;
    const int m0 = w * 16;
    const float* xrow = x0 + (size_t)(m0 + lm) * DM;

    f32x4 acc[NTT];
#pragma unroll
    for (int nt = 0; nt < NTT; ++nt) acc[nt] = (f32x4){0.f, 0.f, 0.f, 0.f};

#pragma unroll
    for (int ks = 0; ks < KST; ++ks) {
        const int k0 = ks * 32 + quad * 8;
        bf16x8 a_h = bf8zero(), a_l = bf8zero();
        if (k0 + 8 <= DM) {      // ks=6: only quad 0 (k=192..199) has data
            const float4 xa = *(const float4*)(xrow + k0);
            const float4 xb = *(const float4*)(xrow + k0 + 4);
            split8(xa, xb, a_h, a_l);
        }
        const unsigned short* ph = Ph + ((ks * NTT) << 9) + (lane << 3);
        const unsigned short* pl = Pl + ((ks * NTT) << 9) + (lane << 3);
#pragma unroll
        for (int nt = 0; nt < NTT; ++nt) {
            const bf16x8 b_h = *(const bf16x8*)(ph + (nt << 9));
            const bf16x8 b_l = *(const bf16x8*)(pl + (nt << 9));
            acc[nt] = __builtin_amdgcn_mfma_f32_16x16x32_bf16(a_h, b_h, acc[nt], 0, 0, 0);
            acc[nt] = __builtin_amdgcn_mfma_f32_16x16x32_bf16(a_l, b_h, acc[nt], 0, 0, 0);
            acc[nt] = __builtin_amdgcn_mfma_f32_16x16x32_bf16(a_h, b_l, acc[nt], 0, 0, 0);
        }
    }
#pragma unroll
    for (int nt = 0; nt < NTT; ++nt) {
        const int col = nt * 16 + lm;
        if (col < DM) {
            const float bs = bias[col];
#pragma unroll
            for (int reg = 0; reg < 4; ++reg) {
                const int row = m0 + quad * 4 + reg;
                const float v = acc[nt][reg] + bs;
                if (BF16OUT)
                    ((unsigned short*)outp)[(size_t)row * DM + col] = f2bf(v);
                else
                    ((float*)outp)[(size_t)row * DM + col] = v;
            }
        }
    }
}

// K4: q projection for the selected band -> bf16 (attn rounds Q to bf16
// anyway, so store bf16 directly; numerics unchanged after rounding).
__global__ __launch_bounds__(256) void k_qproj_mfma(
    const float* __restrict__ bands, const int* __restrict__ sel,
    const unsigned short* __restrict__ WqHp, const unsigned short* __restrict__ WqLp,
    const float* __restrict__ ipb, unsigned short* __restrict__ qb)
{
    const int b = blockIdx.x;
    const int band = sel[b];
    const float* x0 = bands + (size_t)((band * BATCH + b) * KQN) * DM;
    proj_core<true>(x0, WqHp, WqLp, ipb, qb + (size_t)(b * KQN) * DM);
}

// K7: out = o @ out_w^T + out_b (fp32 out)
__global__ __launch_bounds__(256) void k_outproj_mfma(
    const float* __restrict__ obuf, const unsigned short* __restrict__ OwHp,
    const unsigned short* __restrict__ OwLp, const float* __restrict__ outb,
    float* __restrict__ out)
{
    const int b = blockIdx.x;
    proj_core<false>(obuf + (size_t)(b * KQN) * DM, OwHp, OwLp, outb,
                     out + (size_t)(b * KQN) * DM);
}

// ---------------------------------------------------------------------------
// K5: kv projection as bf16 MFMA GEMM (unchanged).
// ---------------------------------------------------------------------------
__global__ __launch_bounds__(256) void k_kvproj(
    const float* __restrict__ bands, const unsigned short* __restrict__ Wb,
    const float* __restrict__ ipb, __hip_bfloat16* __restrict__ Kp,
    __hip_bfloat16* __restrict__ Vp)
{
    __shared__ __align__(16) unsigned short Xs[64][KPAD];
    __shared__ __align__(16) unsigned short Ws[80][KPAD];
    __shared__ float Bbias[80];
    const int t  = threadIdx.x;
    const int M0 = blockIdx.x * 64;     // global kv row base
    const int n0 = blockIdx.y * 80;     // output col base (0..400)

    {
        const float4* wsrc = (const float4*)(Wb + (size_t)n0 * KPAD);
        float4* wdst = (float4*)&Ws[0][0];
        for (int i = t; i < 2320; i += 256) wdst[i] = wsrc[i];
    }
    if (t < 80) Bbias[t] = ipb[DM + n0 + t];
    for (int i = t; i < 64 * 50; i += 256) {
        const int r = i / 50, g = i - r * 50;
        const int gg = M0 + r;
        const int bb = gg / TKV, tk = gg - bb * TKV;
        const int band = tk >> 6, kk = tk & 63;
        const float4 x4 = *(const float4*)(bands
            + ((size_t)((band * BATCH + bb) * KQN + kk)) * DM + g * 4);
        ushort4 u;
        u.x = f2bf(x4.x); u.y = f2bf(x4.y); u.z = f2bf(x4.z); u.w = f2bf(x4.w);
        *(ushort4*)&Xs[r][g * 4] = u;
    }
    for (int i = t; i < 64 * 8; i += 256) {
        const int r = i >> 3, g = i & 7;
        ushort4 z; z.x = 0; z.y = 0; z.z = 0; z.w = 0;
        *(ushort4*)&Xs[r][DM + g * 4] = z;
    }
    __syncthreads();

    const int w = t >> 6, lane = t & 63;
    const int lm = lane & 15, quad = lane >> 4;
    const int m0 = w * 16;
    f32x4 acc[5];
#pragma unroll
    for (int nt = 0; nt < 5; ++nt) acc[nt] = (f32x4){0.f, 0.f, 0.f, 0.f};

#pragma unroll
    for (int ks = 0; ks < 7; ++ks) {                 // 7*32 = 224 >= 200
        const int ka = ks * 32 + quad * 8;
        const bf16x8 a = *(const bf16x8*)&Xs[m0 + lm][ka];
#pragma unroll
        for (int nt = 0; nt < 5; ++nt) {
            const bf16x8 bb8 = *(const bf16x8*)&Ws[nt * 16 + lm][ka];
            acc[nt] = __builtin_amdgcn_mfma_f32_16x16x32_bf16(a, bb8, acc[nt], 0, 0, 0);
        }
    }
#pragma unroll
    for (int nt = 0; nt < 5; ++nt) {
        const int col = n0 + nt * 16 + lm;
        const float bias = Bbias[nt * 16 + lm];
#pragma unroll
        for (int reg = 0; reg < 4; ++reg) {
            const int grow = M0 + m0 + quad * 4 + reg;
            const float v = acc[nt][reg] + bias;
            if (col < DM) Kp[(size_t)grow * DM + col] = __float2bfloat16(v);
            else          Vp[(size_t)grow * DM + (col - DM)] = __float2bfloat16(v);
        }
    }
}

// ---------------------------------------------------------------------------
// K6: MFMA attention per (b, head). Q now read as bf16.
// ---------------------------------------------------------------------------
__global__ __launch_bounds__(256) void k_attn(
    const unsigned short* __restrict__ qb, const __hip_bfloat16* __restrict__ Kp,
    const __hip_bfloat16* __restrict__ Vp, float* __restrict__ obuf)
{
    __shared__ __align__(16) unsigned short Qs[64][72];    // [query][k 0..63]
    __shared__ __align__(16) unsigned short KP[320][72];   // [key][k 0..63]
    __shared__ __align__(16) unsigned short Vt[64][328];   // [e][key]
    __shared__ __align__(16) unsigned short Ps[64][328];   // [query][key]
    const int b = blockIdx.x, hh = blockIdx.y;
    const int t = threadIdx.x;

    const unsigned short* qbase = qb + (size_t)(b * KQN) * DM + hh * HD;
    for (int idx = t; idx < 64 * 64; idx += 256) {
        const int r = idx >> 6, e = idx & 63;
        Qs[r][e] = (e < HD) ? qbase[(size_t)r * DM + e] : 0;
    }
    const unsigned short* kbase = (const unsigned short*)Kp + (size_t)b * TKV * DM + hh * HD;
    for (int idx = t; idx < 320 * 25; idx += 256) {
        const int key = idx / 25, g = idx - key * 25;
        *(unsigned int*)&KP[key][g * 2] =
            *(const unsigned int*)(kbase + (size_t)key * DM + g * 2);
    }
    for (int idx = t; idx < 320 * 7; idx += 256) {   // zero k-pad [50,64)
        const int key = idx / 7, g = idx - key * 7;
        *(unsigned int*)&KP[key][50 + g * 2] = 0;
    }
    const unsigned short* vbase = (const unsigned short*)Vp + (size_t)b * TKV * DM + hh * HD;
    for (int idx = t; idx < 320 * 25; idx += 256) {
        const int key = idx / 25, g = idx - key * 25;
        const unsigned int v = *(const unsigned int*)(vbase + (size_t)key * DM + g * 2);
        Vt[g * 2][key]     = (unsigned short)(v & 0xffffu);
        Vt[g * 2 + 1][key] = (unsigned short)(v >> 16);
    }
    __syncthreads();

    const int w = t >> 6, lane = t & 63;
    const int lm = lane & 15, quad = lane >> 4;
    const int m0 = w * 16;

    f32x4 s[20];
#pragma unroll
    for (int nt = 0; nt < 20; ++nt) s[nt] = (f32x4){0.f, 0.f, 0.f, 0.f};
#pragma unroll
    for (int ks = 0; ks < 2; ++ks) {
        const int ka = ks * 32 + quad * 8;
        const bf16x8 a = *(const bf16x8*)&Qs[m0 + lm][ka];
#pragma unroll
        for (int nt = 0; nt < 20; ++nt) {
            const bf16x8 bb8 = *(const bf16x8*)&KP[nt * 16 + lm][ka];
            s[nt] = __builtin_amdgcn_mfma_f32_16x16x32_bf16(a, bb8, s[nt], 0, 0, 0);
        }
    }

    const float scale = 0.14142135623730951f;  // 1/sqrt(50)
    float inv[4];
#pragma unroll
    for (int reg = 0; reg < 4; ++reg) {
        float mx = -1e30f;
#pragma unroll
        for (int nt = 0; nt < 20; ++nt) {
            const float sv = s[nt][reg] * scale;
            s[nt][reg] = sv;
            mx = fmaxf(mx, sv);
        }
#pragma unroll
        for (int off = 1; off < 16; off <<= 1)
            mx = fmaxf(mx, __shfl_xor(mx, off, 64));
        float lsum = 0.f;
#pragma unroll
        for (int nt = 0; nt < 20; ++nt) {
            const float p = __expf(s[nt][reg] - mx);
            s[nt][reg] = p;
            lsum += p;
        }
#pragma unroll
        for (int off = 1; off < 16; off <<= 1)
            lsum += __shfl_xor(lsum, off, 64);
        inv[reg] = 1.f / lsum;
    }
#pragma unroll
    for (int reg = 0; reg < 4; ++reg) {
        const int row = m0 + quad * 4 + reg;
#pragma unroll
        for (int nt = 0; nt < 20; ++nt)
            Ps[row][nt * 16 + lm] = f2bf(s[nt][reg]);
    }
    __syncthreads();

    f32x4 o[4];
#pragma unroll
    for (int nt = 0; nt < 4; ++nt) o[nt] = (f32x4){0.f, 0.f, 0.f, 0.f};
#pragma unroll
    for (int ks = 0; ks < 10; ++ks) {
        const int ka = ks * 32 + quad * 8;
        const bf16x8 a = *(const bf16x8*)&Ps[m0 + lm][ka];
#pragma unroll
        for (int nt = 0; nt < 4; ++nt) {
            const bf16x8 bb8 = *(const bf16x8*)&Vt[nt * 16 + lm][ka];
            o[nt] = __builtin_amdgcn_mfma_f32_16x16x32_bf16(a, bb8, o[nt], 0, 0, 0);
        }
    }
    float* op = obuf + (size_t)(b * KQN) * DM + hh * HD;
#pragma unroll
    for (int nt = 0; nt < 4; ++nt) {
        const int e = nt * 16 + lm;
        if (e < HD) {
#pragma unroll
            for (int reg = 0; reg < 4; ++reg) {
                const int row = m0 + quad * 4 + reg;
                op[(size_t)row * DM + e] = o[nt][reg] * inv[reg];
            }
        }
    }
}

// ---------------------------------------------------------------------------
// Workspace layout (phase-overlapped, peak 184.1 MB < 193 MB):
//   sel  int [512]               @ 0           (2,048)      [live whole run]
//   -- phase 1 (router):
//   part fp32 [20][512][512]     @ 4096        (20,971,520)
//   h    fp32 [512][512]         @ 20,975,616  ( 1,048,576)
//   -- phase 2 (overlaps part/h after argmax):
//   q    bf16 [512][64][200]     @ 4096        (13,107,200)
//   Wb   bf16 [400][232]         @ 26,218,496  (   185,600)
//   WqHp bf16 packed             @ 26,404,096  (    93,184)
//   WqLp bf16 packed             @ 26,497,280  (    93,184)
//   OwHp bf16 packed             @ 26,590,464  (    93,184)
//   OwLp bf16 packed             @ 26,683,648  (    93,184)
//   Kp   bf16 [512][320][200]    @ 26,776,832  (65,536,000)
//   Vp   bf16 [512][320][200]    @ 92,312,832  (65,536,000)
//   obuf fp32 [512][64][200]     @ 157,848,832 (26,214,400) -> 184,063,232
// ---------------------------------------------------------------------------
extern "C" void kernel_launch(void* const* d_in, const int* in_sizes, int n_in,
                              void* d_out, int out_size, void* d_ws, size_t ws_size,
                              hipStream_t stream)
{
    const float* bands = (const float*)d_in[0];
    const float* w1    = (const float*)d_in[1];
    const float* b1    = (const float*)d_in[2];
    const float* w2    = (const float*)d_in[3];
    const float* b2    = (const float*)d_in[4];
    const float* ipw   = (const float*)d_in[5];
    const float* ipb   = (const float*)d_in[6];
    const float* outw  = (const float*)d_in[7];
    const float* outb  = (const float*)d_in[8];
    float* out = (float*)d_out;

    if (ws_size < (size_t)192940032) return;

    char* ws = (char*)d_ws;
    int*   sel  = (int*)  (ws + 0);
    float* part = (float*)(ws + 4096);
    float* h    = (float*)(ws + 20975616);
    unsigned short* qb = (unsigned short*)(ws + 4096);   // phase 2 (part dead)
    unsigned short* Wb = (unsigned short*)(ws + 26218496);
    unsigned short* WqHp = (unsigned short*)(ws + 26404096);
    unsigned short* WqLp = (unsigned short*)(ws + 26497280);
    unsigned short* OwHp = (unsigned short*)(ws + 26590464);
    unsigned short* OwLp = (unsigned short*)(ws + 26683648);
    __hip_bfloat16* Kp = (__hip_bfloat16*)(ws + 26776832);
    __hip_bfloat16* Vp = (__hip_bfloat16*)(ws + 92312832);
    float* obuf = (float*)(ws + 157848832);

    // weight preps (independent of router; regions disjoint from part/h)
    k_wprep<<<400, 256, 0, stream>>>(ipw, Wb);
    k_wpack<<<dim3(KST * NTT, 2), 256, 0, stream>>>(ipw, outw, WqHp, WqLp, OwHp, OwLp);

    k_router_mfma<<<dim3(8, 8, KSPLIT), 256, 0, stream>>>(bands, w1, part);
    k_reduce_relu<<<(BATCH * HIDW) / 256, 256, 0, stream>>>(part, b1, h);
    k_argmax<<<BATCH, 256, 0, stream>>>(h, w2, b2, sel);
    // ---- phase 2: phase-1 buffers (part/h) are dead from here ----
    k_qproj_mfma<<<BATCH, 256, 0, stream>>>(bands, sel, WqHp, WqLp, ipb, qb);
    k_kvproj<<<dim3(2560, 5), 256, 0, stream>>>(bands, Wb, ipb, Kp, Vp);
    k_attn<<<dim3(BATCH, NHEAD), 256, 0, stream>>>(qb, Kp, Vp, obuf);
    k_outproj_mfma<<<BATCH, 256, 0, stream>>>(obuf, OwHp, OwLp, outb, out);
}